// Round 1
// baseline (461.904 us; speedup 1.0000x reference)
//
#include <hip/hip_runtime.h>

// ModelQuantLinear: int8-act × int4-weight per-tensor quantized linear, 8192×4096 @ 4096×4096^T.
// Exact integer GEMM (mfma_i32_16x16x64_i8) in dequantized-equivalent form.

typedef int v4i __attribute__((ext_vector_type(4)));

#define AS1(p) ((const __attribute__((address_space(1))) void*)(p))
#define AS3(p) ((__attribute__((address_space(3))) void*)(p))

#define GM 8192
#define GN 4096
#define GK 4096

// ---------------- max|x| reduction (float4, wave-reduce, atomicMax on float bits) -------------
__global__ __launch_bounds__(256) void maxabs_kernel(const float* __restrict__ x, int n4,
                                                     unsigned* __restrict__ slot) {
  int tid = blockIdx.x * blockDim.x + threadIdx.x;
  int stride = gridDim.x * blockDim.x;
  float m = 0.0f;
  const float4* x4 = (const float4*)x;
  for (int i = tid; i < n4; i += stride) {
    float4 v = x4[i];
    m = fmaxf(m, fmaxf(fmaxf(fabsf(v.x), fabsf(v.y)), fmaxf(fabsf(v.z), fabsf(v.w))));
  }
  for (int off = 32; off; off >>= 1) m = fmaxf(m, __shfl_xor(m, off));
  if ((threadIdx.x & 63) == 0) atomicMax(slot, __float_as_uint(m));
}

// ---------------- per-tensor quantize to int8 storage --------------------------------------
__global__ __launch_bounds__(256) void quant_kernel(const float* __restrict__ x,
                                                    signed char* __restrict__ q, int n4,
                                                    const unsigned* __restrict__ slot,
                                                    float qmaxv, float qlo, float qhi) {
  float s = fmaxf(__uint_as_float(*slot) / qmaxv, 1e-8f);
  int tid = blockIdx.x * blockDim.x + threadIdx.x;
  int stride = gridDim.x * blockDim.x;
  const float4* x4 = (const float4*)x;
  int* q4 = (int*)q;
  for (int i = tid; i < n4; i += stride) {
    float4 v = x4[i];
    int a0 = (int)fminf(fmaxf(rintf(v.x / s), qlo), qhi);
    int a1 = (int)fminf(fmaxf(rintf(v.y / s), qlo), qhi);
    int a2 = (int)fminf(fmaxf(rintf(v.z / s), qlo), qhi);
    int a3 = (int)fminf(fmaxf(rintf(v.w / s), qlo), qhi);
    q4[i] = (a0 & 255) | ((a1 & 255) << 8) | ((a2 & 255) << 16) | ((a3 & 255) << 24);
  }
}

// ---------------- i8 GEMM: C[t][o] = sum_k Xq[t][k]*Wq[o][k]; epilogue fuses bias + y write + max|y|
// 128x128 tile, BK=64, 4 waves (2x2), mfma_i32_16x16x64_i8, global_load_lds staging.
// LDS bank-conflict fix: granule swizzle g_phys = g_log ^ ((row>>1)&3), applied on the
// GLOBAL source address (global_load_lds dest must stay linear) and on the ds_read side.
__global__ __launch_bounds__(256) void gemm_i8_kernel(const signed char* __restrict__ Xq,
                                                      const signed char* __restrict__ Wq,
                                                      const float* __restrict__ bias,
                                                      const unsigned* __restrict__ slots,
                                                      float* __restrict__ Y,
                                                      unsigned* __restrict__ maxY) {
  __shared__ signed char As[128 * 64];
  __shared__ signed char Bs[128 * 64];
  const int tid = threadIdx.x;
  const int wid = tid >> 6;
  const int lane = tid & 63;
  const int wr = wid >> 1, wc = wid & 1;
  const int lr = lane & 15, lg = lane >> 4;

  const int nbn = GN / 128;  // 32
  const int brow = (int)(blockIdx.x / nbn) * 128;
  const int bcol = (int)(blockIdx.x % nbn) * 128;

  const int sr0 = (wid << 5) + (lane >> 2);  // staging row for j=0; +16 for j=1

  v4i acc[4][4] = {};

  for (int kt = 0; kt < GK; kt += 64) {
#pragma unroll
    for (int j = 0; j < 2; ++j) {
      int r = sr0 + j * 16;
      int cg = (((lane & 3) ^ ((r >> 1) & 3)) << 4);  // inverse-swizzled source granule
      const signed char* ga = Xq + (size_t)(brow + r) * GK + kt + cg;
      const signed char* gb = Wq + (size_t)(bcol + r) * GK + kt + cg;
      __builtin_amdgcn_global_load_lds(AS1(ga), AS3(&As[((wid << 5) + j * 16) * 64]), 16, 0, 0);
      __builtin_amdgcn_global_load_lds(AS1(gb), AS3(&Bs[((wid << 5) + j * 16) * 64]), 16, 0, 0);
    }
    __syncthreads();  // compiler emits s_waitcnt vmcnt(0) before s_barrier -> LDS ready

    v4i af[4], bf[4];
#pragma unroll
    for (int m = 0; m < 4; ++m) {
      int r = wr * 64 + m * 16 + lr;
      af[m] = *(const v4i*)&As[r * 64 + ((lg ^ ((r >> 1) & 3)) << 4)];
    }
#pragma unroll
    for (int n = 0; n < 4; ++n) {
      int r = wc * 64 + n * 16 + lr;
      bf[n] = *(const v4i*)&Bs[r * 64 + ((lg ^ ((r >> 1) & 3)) << 4)];
    }
#pragma unroll
    for (int m = 0; m < 4; ++m)
#pragma unroll
      for (int n = 0; n < 4; ++n)
        acc[m][n] = __builtin_amdgcn_mfma_i32_16x16x64_i8(af[m], bf[n], acc[m][n], 0, 0, 0);
    __syncthreads();
  }

  // Epilogue: y = acc * (s_in*s_w) + round(b/s_b)*s_b ; track max|y|
  float s_in = fmaxf(__uint_as_float(slots[0]) / 127.0f, 1e-8f);
  float s_w  = fmaxf(__uint_as_float(slots[1]) / 7.0f, 1e-8f);
  float s_b  = s_in * s_w;
  float lmax = 0.0f;
#pragma unroll
  for (int n = 0; n < 4; ++n) {
    int o = bcol + wc * 64 + n * 16 + lr;
    float bdq = rintf(bias[o] / s_b) * s_b;
#pragma unroll
    for (int m = 0; m < 4; ++m) {
      int t0 = brow + wr * 64 + m * 16 + (lg << 2);
#pragma unroll
      for (int r2 = 0; r2 < 4; ++r2) {
        float yv = (float)acc[m][n][r2] * s_b + bdq;
        Y[(size_t)(t0 + r2) * GN + o] = yv;
        lmax = fmaxf(lmax, fabsf(yv));
      }
    }
  }
  for (int off = 32; off; off >>= 1) lmax = fmaxf(lmax, __shfl_xor(lmax, off));
  if (lane == 0) atomicMax(maxY, __float_as_uint(lmax));
}

// ---------------- output quant in-place on d_out --------------------------------------------
__global__ __launch_bounds__(256) void quant_out_kernel(float* __restrict__ y, int n4,
                                                        const unsigned* __restrict__ slot) {
  float s = fmaxf(__uint_as_float(*slot) / 127.0f, 1e-8f);
  int tid = blockIdx.x * blockDim.x + threadIdx.x;
  int stride = gridDim.x * blockDim.x;
  float4* y4 = (float4*)y;
  for (int i = tid; i < n4; i += stride) {
    float4 v = y4[i];
    v.x = fminf(fmaxf(rintf(v.x / s), -128.0f), 127.0f) * s;
    v.y = fminf(fmaxf(rintf(v.y / s), -128.0f), 127.0f) * s;
    v.z = fminf(fmaxf(rintf(v.z / s), -128.0f), 127.0f) * s;
    v.w = fminf(fmaxf(rintf(v.w / s), -128.0f), 127.0f) * s;
    y4[i] = v;
  }
}

extern "C" void kernel_launch(void* const* d_in, const int* in_sizes, int n_in,
                              void* d_out, int out_size, void* d_ws, size_t ws_size,
                              hipStream_t stream) {
  const float* inp = (const float*)d_in[0];  // [8192,4096]
  const float* W   = (const float*)d_in[1];  // [4096,4096]
  const float* b   = (const float*)d_in[2];  // [4096]
  float* out = (float*)d_out;                // [8192,4096]

  unsigned* slots = (unsigned*)d_ws;  // [0]=max|X| bits, [1]=max|W| bits, [2]=max|Y| bits
  signed char* Xq = (signed char*)d_ws + 256;
  signed char* Wq = Xq + (size_t)GM * GK;

  const int nX = GM * GK;  // 33554432
  const int nW = GN * GK;  // 16777216

  // zero the atomic-max slots (ws is NOT re-poisoned between timed replays)
  hipMemsetAsync(d_ws, 0, 16, stream);

  maxabs_kernel<<<2048, 256, 0, stream>>>(inp, nX / 4, slots + 0);
  maxabs_kernel<<<1024, 256, 0, stream>>>(W,   nW / 4, slots + 1);

  quant_kernel<<<2048, 256, 0, stream>>>(inp, Xq, nX / 4, slots + 0, 127.0f, -128.0f, 127.0f);
  quant_kernel<<<1024, 256, 0, stream>>>(W,   Wq, nW / 4, slots + 1, 7.0f,   -8.0f,   7.0f);

  gemm_i8_kernel<<<dim3((GM / 128) * (GN / 128)), 256, 0, stream>>>(Xq, Wq, b, slots, out,
                                                                    slots + 2);

  quant_out_kernel<<<2048, 256, 0, stream>>>(out, (GM * GN) / 4, slots + 2);
}

// Round 2
// 285.975 us; speedup vs baseline: 1.6152x; 1.6152x over previous
//
#include <hip/hip_runtime.h>

// ModelQuantLinear: int8-act × int4-weight per-tensor quantized linear, 8192×4096 @ 4096×4096^T.
// Exact integer GEMM via mfma_i32_16x16x64_i8, 256x256 8-phase counted-vmcnt schedule.

typedef int v4i __attribute__((ext_vector_type(4)));

#define AS1(p) ((const __attribute__((address_space(1))) void*)(p))
#define AS3(p) ((__attribute__((address_space(3))) void*)(p))

#define GM 8192
#define GN 4096
#define GK 4096
#define NBN 16  // 4096/256 col tiles
#define NWG 512 // (8192/256)*(4096/256)

// ---------------- max|x| (float4 grid-stride, wave+block reduce, 1 atomic/block) ------------
__global__ __launch_bounds__(256) void maxabs_kernel(const float* __restrict__ x, int n4,
                                                     unsigned* __restrict__ slot) {
  __shared__ float red[4];
  int tid = blockIdx.x * blockDim.x + threadIdx.x;
  int stride = gridDim.x * blockDim.x;
  float m = 0.0f;
  const float4* x4 = (const float4*)x;
  for (int i = tid; i < n4; i += stride) {
    float4 v = x4[i];
    m = fmaxf(m, fmaxf(fmaxf(fabsf(v.x), fabsf(v.y)), fmaxf(fabsf(v.z), fabsf(v.w))));
  }
  for (int off = 32; off; off >>= 1) m = fmaxf(m, __shfl_xor(m, off));
  if ((threadIdx.x & 63) == 0) red[threadIdx.x >> 6] = m;
  __syncthreads();
  if (threadIdx.x == 0) {
    float b = fmaxf(fmaxf(red[0], red[1]), fmaxf(red[2], red[3]));
    atomicMax(slot, __float_as_uint(b));
  }
}

// ---------------- per-tensor quantize to int8 storage (reciprocal-mul, no per-elem div) -----
__global__ __launch_bounds__(256) void quant_kernel(const float* __restrict__ x,
                                                    signed char* __restrict__ q, int n4,
                                                    const unsigned* __restrict__ slot,
                                                    float qmaxv, float qlo, float qhi) {
  float s = fmaxf(__uint_as_float(*slot) / qmaxv, 1e-8f);
  float inv = 1.0f / s;
  int tid = blockIdx.x * blockDim.x + threadIdx.x;
  int stride = gridDim.x * blockDim.x;
  const float4* x4 = (const float4*)x;
  int* q4 = (int*)q;
  for (int i = tid; i < n4; i += stride) {
    float4 v = x4[i];
    int a0 = (int)fminf(fmaxf(rintf(v.x * inv), qlo), qhi);
    int a1 = (int)fminf(fmaxf(rintf(v.y * inv), qlo), qhi);
    int a2 = (int)fminf(fmaxf(rintf(v.z * inv), qlo), qhi);
    int a3 = (int)fminf(fmaxf(rintf(v.w * inv), qlo), qhi);
    q4[i] = (a0 & 255) | ((a1 & 255) << 8) | ((a2 & 255) << 16) | ((a3 & 255) << 24);
  }
}

// ---------------- i8 GEMM, 256x256 tile, BK=128, 8 waves (2Mx4N), 8-phase counted vmcnt -----
// LDS: A/B each 2dbuf x 2half x [128 rows][128 B] = 64 KiB -> 128 KiB total.
// Swizzle: 16B granule g_phys = g_log ^ (row&7); linear gload_lds dest + inverse-swizzled
// global source + swizzled ds_read (both-sides rule).
// Wave (wr,wc) owns rows {wr*64, 128+wr*64}+0..63, cols {wc*32, 128+wc*32}+0..31.
// Phase q=(mh,nh) computes quadrant m in mh*4.., n in nh*2.. over full K=128 (2 MFMA k-slices).
// Prefetch: q0->A1(t+1), q1->B1(t+1), q2->A0(t+2), q3->B0(t+2); vmcnt(4) per K-tile boundary.
__global__ __launch_bounds__(512, 2) void gemm_i8_kernel(const signed char* __restrict__ Xq,
                                                         const signed char* __restrict__ Wq,
                                                         const float* __restrict__ bias,
                                                         const unsigned* __restrict__ slots,
                                                         float* __restrict__ Y,
                                                         unsigned* __restrict__ maxY) {
  __shared__ signed char smem[131072];
  const int tid = threadIdx.x;
  const int wid = tid >> 6, lane = tid & 63;
  const int wr = wid >> 2, wc = wid & 3;
  const int lr = lane & 15, lg = lane >> 4;

  // XCD-aware bijective swizzle (512 % 8 == 0)
  const int bid = (int)blockIdx.x;
  const int swz = (bid & 7) * (NWG / 8) + (bid >> 3);
  const int brow = (swz / NBN) * 256;
  const int bcol = (swz % NBN) * 256;

  // staging thread map: row-in-chunk, physical granule, inverse-swizzled logical granule
  const int srr = tid >> 3;
  const int sgl = (tid & 7) ^ (srr & 7);

#define ASLOT(db, h) (smem + ((db) * 2 + (h)) * 16384)
#define BSLOT(db, h) (smem + 65536 + ((db) * 2 + (h)) * 16384)
// one half-tile (128 rows x 128 B) = 2 x global_load_lds(16B) per wave
#define STAGE(gptr, grow0, kofs, slot)                                                        \
  {                                                                                           \
    const signed char* _s0 = (gptr) + (size_t)((grow0) + srr) * GK + (kofs) + sgl * 16;       \
    __builtin_amdgcn_global_load_lds(AS1(_s0), AS3((slot) + wid * 1024), 16, 0, 0);           \
    __builtin_amdgcn_global_load_lds(AS1(_s0 + (size_t)64 * GK),                              \
                                     AS3((slot) + 8192 + wid * 1024), 16, 0, 0);              \
  }

  // prologue: A0(0) B0(0) A1(0) B1(0) A0(1) B0(1)  (oldest-first; vmcnt(4) -> tile 0 ready)
  STAGE(Xq, brow, 0, ASLOT(0, 0));
  STAGE(Wq, bcol, 0, BSLOT(0, 0));
  STAGE(Xq, brow + 128, 0, ASLOT(0, 1));
  STAGE(Wq, bcol + 128, 0, BSLOT(0, 1));
  STAGE(Xq, brow, 128, ASLOT(1, 0));
  STAGE(Wq, bcol, 128, BSLOT(1, 0));

  v4i acc[8][4] = {};

#pragma unroll 2
  for (int t = 0; t < 32; ++t) {
    const int db = t & 1;
    if (t == 31)
      asm volatile("s_waitcnt vmcnt(0)" ::: "memory");
    else
      asm volatile("s_waitcnt vmcnt(4)" ::: "memory");
    __builtin_amdgcn_s_barrier();
#pragma unroll
    for (int q = 0; q < 4; ++q) {
      const int mh = q >> 1, nh = q & 1;
      const signed char* Abuf = ASLOT(db, mh);
      const signed char* Bbuf = BSLOT(db, nh);
      v4i af[4][2], bf[2][2];
#pragma unroll
      for (int mm = 0; mm < 4; ++mm) {
        int hr = wr * 64 + mm * 16 + lr;
        int sw = hr & 7;
#pragma unroll
        for (int kk = 0; kk < 2; ++kk)
          af[mm][kk] = *(const v4i*)(Abuf + hr * 128 + (((kk * 4 + lg) ^ sw) << 4));
      }
#pragma unroll
      for (int nn = 0; nn < 2; ++nn) {
        int hr = wc * 32 + nn * 16 + lr;
        int sw = hr & 7;
#pragma unroll
        for (int kk = 0; kk < 2; ++kk)
          bf[nn][kk] = *(const v4i*)(Bbuf + hr * 128 + (((kk * 4 + lg) ^ sw) << 4));
      }
      if (q == 0 && t + 1 < 32) STAGE(Xq, brow + 128, (t + 1) * 128, ASLOT((t + 1) & 1, 1));
      if (q == 1 && t + 1 < 32) STAGE(Wq, bcol + 128, (t + 1) * 128, BSLOT((t + 1) & 1, 1));
      if (q == 2 && t + 2 < 32) STAGE(Xq, brow, (t + 2) * 128, ASLOT(db, 0));
      if (q == 3 && t + 2 < 32) STAGE(Wq, bcol, (t + 2) * 128, BSLOT(db, 0));
      __builtin_amdgcn_s_barrier();
      asm volatile("s_waitcnt lgkmcnt(0)");
      __builtin_amdgcn_s_setprio(1);
#pragma unroll
      for (int mm = 0; mm < 4; ++mm)
#pragma unroll
        for (int nn = 0; nn < 2; ++nn)
#pragma unroll
          for (int kk = 0; kk < 2; ++kk)
            acc[mh * 4 + mm][nh * 2 + nn] = __builtin_amdgcn_mfma_i32_16x16x64_i8(
                af[mm][kk], bf[nn][kk], acc[mh * 4 + mm][nh * 2 + nn], 0, 0, 0);
      __builtin_amdgcn_s_setprio(0);
      __builtin_amdgcn_s_barrier();
    }
  }

  // Epilogue: y = acc*(s_in*s_w) + round(b/s_b)*s_b ; track max|y| (block-reduced atomic)
  float s_in = fmaxf(__uint_as_float(slots[0]) / 127.0f, 1e-8f);
  float s_w = fmaxf(__uint_as_float(slots[1]) / 7.0f, 1e-8f);
  float s_b = s_in * s_w;
  float lmax = 0.0f;
#pragma unroll
  for (int n = 0; n < 4; ++n) {
    int o = bcol + (n >> 1) * 128 + wc * 32 + (n & 1) * 16 + lr;
    float bdq = rintf(bias[o] / s_b) * s_b;
#pragma unroll
    for (int m = 0; m < 8; ++m) {
      int t0 = brow + (m >> 2) * 128 + wr * 64 + (m & 3) * 16 + (lg << 2);
#pragma unroll
      for (int r2 = 0; r2 < 4; ++r2) {
        float yv = (float)acc[m][n][r2] * s_b + bdq;
        Y[(size_t)(t0 + r2) * GN + o] = yv;
        lmax = fmaxf(lmax, fabsf(yv));
      }
    }
  }
  for (int off = 32; off; off >>= 1) lmax = fmaxf(lmax, __shfl_xor(lmax, off));
  float* fred = (float*)smem;  // K-loop done for all waves (last phase barrier) -> safe reuse
  if (lane == 0) fred[wid] = lmax;
  __syncthreads();
  if (tid == 0) {
    float m = fred[0];
#pragma unroll
    for (int i = 1; i < 8; ++i) m = fmaxf(m, fred[i]);
    atomicMax(maxY, __float_as_uint(m));
  }
#undef STAGE
#undef ASLOT
#undef BSLOT
}

// ---------------- output quant in-place on d_out --------------------------------------------
__global__ __launch_bounds__(256) void quant_out_kernel(float* __restrict__ y, int n4,
                                                        const unsigned* __restrict__ slot) {
  float s = fmaxf(__uint_as_float(*slot) / 127.0f, 1e-8f);
  float inv = 1.0f / s;
  int tid = blockIdx.x * blockDim.x + threadIdx.x;
  int stride = gridDim.x * blockDim.x;
  float4* y4 = (float4*)y;
  for (int i = tid; i < n4; i += stride) {
    float4 v = y4[i];
    v.x = fminf(fmaxf(rintf(v.x * inv), -128.0f), 127.0f) * s;
    v.y = fminf(fmaxf(rintf(v.y * inv), -128.0f), 127.0f) * s;
    v.z = fminf(fmaxf(rintf(v.z * inv), -128.0f), 127.0f) * s;
    v.w = fminf(fmaxf(rintf(v.w * inv), -128.0f), 127.0f) * s;
    y4[i] = v;
  }
}

extern "C" void kernel_launch(void* const* d_in, const int* in_sizes, int n_in,
                              void* d_out, int out_size, void* d_ws, size_t ws_size,
                              hipStream_t stream) {
  const float* inp = (const float*)d_in[0];  // [8192,4096]
  const float* W = (const float*)d_in[1];    // [4096,4096]
  const float* b = (const float*)d_in[2];    // [4096]
  float* out = (float*)d_out;                // [8192,4096]

  unsigned* slots = (unsigned*)d_ws;  // [0]=max|X|, [1]=max|W|, [2]=max|Y| (float bits)
  signed char* Xq = (signed char*)d_ws + 256;
  signed char* Wq = Xq + (size_t)GM * GK;

  const int nX = GM * GK;  // 33554432
  const int nW = GN * GK;  // 16777216

  // zero the atomic-max slots (ws is NOT re-poisoned between timed replays)
  hipMemsetAsync(d_ws, 0, 16, stream);

  maxabs_kernel<<<1024, 256, 0, stream>>>(inp, nX / 4, slots + 0);
  maxabs_kernel<<<512, 256, 0, stream>>>(W, nW / 4, slots + 1);

  quant_kernel<<<1024, 256, 0, stream>>>(inp, Xq, nX / 4, slots + 0, 127.0f, -128.0f, 127.0f);
  quant_kernel<<<512, 256, 0, stream>>>(W, Wq, nW / 4, slots + 1, 7.0f, -8.0f, 7.0f);

  gemm_i8_kernel<<<NWG, 512, 0, stream>>>(Xq, Wq, b, slots, out, slots + 2);

  quant_out_kernel<<<1024, 256, 0, stream>>>(out, (GM * GN) / 4, slots + 2);
}

// Round 4
// 265.862 us; speedup vs baseline: 1.7374x; 1.0757x over previous
//
#include <hip/hip_runtime.h>

// ModelQuantLinear: int8-act × int4-weight per-tensor quantized linear, 8192×4096 @ 4096×4096^T.
// Exact integer GEMM via mfma_i32_16x16x64_i8, 256x256 tile, 4-phase read-partitioned schedule.
// 24 ds_read_b128 per K-tile (bf frags persist across M-half phases); tile-ready vmcnt+barrier
// BEFORE any ds_read of that tile (round-3 race fixed).

typedef int v4i __attribute__((ext_vector_type(4)));

#define AS1(p) ((const __attribute__((address_space(1))) void*)(p))
#define AS3(p) ((__attribute__((address_space(3))) void*)(p))

#define GM 8192
#define GN 4096
#define GK 4096
#define NBN 16   // 4096/256 col tiles
#define NWG 512  // (8192/256)*(4096/256)

// ---------------- max|x| (float4 grid-stride, wave+block reduce, 1 atomic/block) ------------
__global__ __launch_bounds__(256) void maxabs_kernel(const float* __restrict__ x, int n4,
                                                     unsigned* __restrict__ slot) {
  __shared__ float red[4];
  int tid = blockIdx.x * blockDim.x + threadIdx.x;
  int stride = gridDim.x * blockDim.x;
  float m = 0.0f;
  const float4* x4 = (const float4*)x;
  for (int i = tid; i < n4; i += stride) {
    float4 v = x4[i];
    m = fmaxf(m, fmaxf(fmaxf(fabsf(v.x), fabsf(v.y)), fmaxf(fabsf(v.z), fabsf(v.w))));
  }
  for (int off = 32; off; off >>= 1) m = fmaxf(m, __shfl_xor(m, off));
  if ((threadIdx.x & 63) == 0) red[threadIdx.x >> 6] = m;
  __syncthreads();
  if (threadIdx.x == 0) {
    float b = fmaxf(fmaxf(red[0], red[1]), fmaxf(red[2], red[3]));
    atomicMax(slot, __float_as_uint(b));
  }
}

// ---------------- per-tensor quantize to int8 storage (reciprocal-mul) ----------------------
__global__ __launch_bounds__(256) void quant_kernel(const float* __restrict__ x,
                                                    signed char* __restrict__ q, int n4,
                                                    const unsigned* __restrict__ slot,
                                                    float qmaxv, float qlo, float qhi) {
  float s = fmaxf(__uint_as_float(*slot) / qmaxv, 1e-8f);
  float inv = 1.0f / s;
  int tid = blockIdx.x * blockDim.x + threadIdx.x;
  int stride = gridDim.x * blockDim.x;
  const float4* x4 = (const float4*)x;
  int* q4 = (int*)q;
  for (int i = tid; i < n4; i += stride) {
    float4 v = x4[i];
    int a0 = (int)fminf(fmaxf(rintf(v.x * inv), qlo), qhi);
    int a1 = (int)fminf(fmaxf(rintf(v.y * inv), qlo), qhi);
    int a2 = (int)fminf(fmaxf(rintf(v.z * inv), qlo), qhi);
    int a3 = (int)fminf(fmaxf(rintf(v.w * inv), qlo), qhi);
    q4[i] = (a0 & 255) | ((a1 & 255) << 8) | ((a2 & 255) << 16) | ((a3 & 255) << 24);
  }
}

// ---------------- i8 GEMM, 256x256 tile, BK=128 B, 8 waves (2Mx4N) ---------------------------
// Per tile t (buffer db=t&1; stages target ndb):
//   pre-P0: issue STAGE B0(t+1); vmcnt(2) [t=31: vmcnt(0)]; barrier  -> tile t fully in LDS
//   P0: read af[0..3]@k0 + bf[0..3]@k0 (8); issue B1(t+1); lgkmcnt(0); MFMA16(0); barrier
//   P1: read af[4..7]@k0 (4);               issue A0(t+1); lgkmcnt(0); MFMA16(4); barrier
//   P2: read af[0..3]@k1 + bf[0..3]@k1 (8); issue A1(t+1); lgkmcnt(0); MFMA16(0); barrier
//   P3: read af[4..7]@k1 (4);                              lgkmcnt(0); MFMA16(4); barrier
// vmcnt(2) at tile start: outstanding = leftover B0(t+1)(2 were left? no: 2 left at prior wait)
//   = 2 + 6 issued during tile t-1 + 2 just issued = 10; waiting to 2 drains exactly the four
//   halves of tile t. Buffer db restage begins at tile t+1 pre-P0, after tile t's P3 barrier,
//   by which point all reads of db completed (lgkmcnt(0) precedes MFMA precedes barrier).
// Swizzle: 16B granule g_phys = g_log ^ (row&7), inverse-applied on global source (rule 21).
__global__ __launch_bounds__(512, 2) void gemm_i8_kernel(const signed char* __restrict__ Xq,
                                                         const signed char* __restrict__ Wq,
                                                         const float* __restrict__ bias,
                                                         const unsigned* __restrict__ slots,
                                                         float* __restrict__ Y,
                                                         unsigned* __restrict__ maxY) {
  __shared__ signed char smem[131072];
  const int tid = threadIdx.x;
  const int wid = tid >> 6, lane = tid & 63;
  const int wr = wid >> 2, wc = wid & 3;
  const int lr = lane & 15, lg = lane >> 4;

  // XCD-aware bijective swizzle (512 % 8 == 0)
  const int bid = (int)blockIdx.x;
  const int swz = (bid & 7) * (NWG / 8) + (bid >> 3);
  const int brow = (swz / NBN) * 256;
  const int bcol = (swz % NBN) * 256;

  // staging thread map: row-in-half, inverse-swizzled source granule
  const int srr = tid >> 3;
  const int sgl = (tid & 7) ^ (srr & 7);

  // per-frag LDS row offsets / swizzle keys (invariant over tiles & kslices)
  int aoff[4], asw[4], boff[4], bsw[4];
#pragma unroll
  for (int mm = 0; mm < 4; ++mm) {
    int hr = wr * 64 + mm * 16 + lr;
    aoff[mm] = hr * 128;
    asw[mm] = hr & 7;
  }
#pragma unroll
  for (int nn = 0; nn < 4; ++nn) {
    int hr = wc * 32 + (nn & 1) * 16 + lr;
    boff[nn] = hr * 128;
    bsw[nn] = hr & 7;
  }

#define ASLOT(db, h) (smem + ((db) * 2 + (h)) * 16384)
#define BSLOT(db, h) (smem + 65536 + ((db) * 2 + (h)) * 16384)
// one half-tile (128 rows x 128 B) = 2 x global_load_lds(16B) per wave
#define STAGE(gptr, grow0, kofs, slot)                                                        \
  {                                                                                           \
    const signed char* _s0 = (gptr) + (size_t)((grow0) + srr) * GK + (kofs) + sgl * 16;       \
    __builtin_amdgcn_global_load_lds(AS1(_s0), AS3((slot) + wid * 1024), 16, 0, 0);           \
    __builtin_amdgcn_global_load_lds(AS1(_s0 + (size_t)64 * GK),                              \
                                     AS3((slot) + 8192 + wid * 1024), 16, 0, 0);              \
  }
#define LDA(mm, db, h, kk) \
  *(const v4i*)(ASLOT(db, h) + aoff[mm] + ((((kk)*4 + lg) ^ asw[mm]) << 4))
#define LDB(nn, db, kk) \
  *(const v4i*)(BSLOT(db, (nn) >> 1) + boff[nn] + ((((kk)*4 + lg) ^ bsw[nn]) << 4))
#define MFMA16(arow)                                                                          \
  __builtin_amdgcn_s_setprio(1);                                                              \
  _Pragma("unroll") for (int mm = 0; mm < 4; ++mm)                                            \
      _Pragma("unroll") for (int nn = 0; nn < 4; ++nn)                                        \
          acc[(arow) + mm][nn] =                                                              \
      __builtin_amdgcn_mfma_i32_16x16x64_i8(af[mm], bf[nn], acc[(arow) + mm][nn], 0, 0, 0);   \
  __builtin_amdgcn_s_setprio(0);

  // prologue: tile 0's four halves (same order as steady-state issue)
  STAGE(Wq, bcol, 0, BSLOT(0, 0));
  STAGE(Wq, bcol + 128, 0, BSLOT(0, 1));
  STAGE(Xq, brow, 0, ASLOT(0, 0));
  STAGE(Xq, brow + 128, 0, ASLOT(0, 1));

  v4i acc[8][4] = {};

#pragma unroll 2
  for (int t = 0; t < 32; ++t) {
    const int db = t & 1, ndb = db ^ 1;
    const int kof = (t + 1) * 128;
    v4i af[4], bf[4];

    // tile-ready gate: issue next B0, then drain this tile's four halves
    if (t < 31) STAGE(Wq, bcol, kof, BSLOT(ndb, 0));
    if (t == 31)
      asm volatile("s_waitcnt vmcnt(0)" ::: "memory");
    else
      asm volatile("s_waitcnt vmcnt(2)" ::: "memory");
    __builtin_amdgcn_s_barrier();

    // ---- P0: kk=0, mh=0 (+ bf@k0); stage B1(t+1)
#pragma unroll
    for (int mm = 0; mm < 4; ++mm) af[mm] = LDA(mm, db, 0, 0);
#pragma unroll
    for (int nn = 0; nn < 4; ++nn) bf[nn] = LDB(nn, db, 0);
    if (t < 31) STAGE(Wq, bcol + 128, kof, BSLOT(ndb, 1));
    asm volatile("s_waitcnt lgkmcnt(0)");
    MFMA16(0)
    __builtin_amdgcn_s_barrier();

    // ---- P1: kk=0, mh=1 (bf persists); stage A0(t+1)
#pragma unroll
    for (int mm = 0; mm < 4; ++mm) af[mm] = LDA(mm, db, 1, 0);
    if (t < 31) STAGE(Xq, brow, kof, ASLOT(ndb, 0));
    asm volatile("s_waitcnt lgkmcnt(0)");
    MFMA16(4)
    __builtin_amdgcn_s_barrier();

    // ---- P2: kk=1, mh=0 (+ bf@k1); stage A1(t+1)
#pragma unroll
    for (int mm = 0; mm < 4; ++mm) af[mm] = LDA(mm, db, 0, 1);
#pragma unroll
    for (int nn = 0; nn < 4; ++nn) bf[nn] = LDB(nn, db, 1);
    if (t < 31) STAGE(Xq, brow + 128, kof, ASLOT(ndb, 1));
    asm volatile("s_waitcnt lgkmcnt(0)");
    MFMA16(0)
    __builtin_amdgcn_s_barrier();

    // ---- P3: kk=1, mh=1 (bf persists)
#pragma unroll
    for (int mm = 0; mm < 4; ++mm) af[mm] = LDA(mm, db, 1, 1);
    asm volatile("s_waitcnt lgkmcnt(0)");
    MFMA16(4)
    __builtin_amdgcn_s_barrier();
  }

  // Epilogue: y = acc*(s_in*s_w) + round(b/s_b)*s_b ; track max|y| (block-reduced atomic)
  float s_in = fmaxf(__uint_as_float(slots[0]) / 127.0f, 1e-8f);
  float s_w = fmaxf(__uint_as_float(slots[1]) / 7.0f, 1e-8f);
  float s_b = s_in * s_w;
  float lmax = 0.0f;
#pragma unroll
  for (int n = 0; n < 4; ++n) {
    int o = bcol + (n >> 1) * 128 + wc * 32 + (n & 1) * 16 + lr;
    float bdq = rintf(bias[o] / s_b) * s_b;
#pragma unroll
    for (int m = 0; m < 8; ++m) {
      int t0 = brow + (m >> 2) * 128 + wr * 64 + (m & 3) * 16 + (lg << 2);
#pragma unroll
      for (int r2 = 0; r2 < 4; ++r2) {
        float yv = (float)acc[m][n][r2] * s_b + bdq;
        Y[(size_t)(t0 + r2) * GN + o] = yv;
        lmax = fmaxf(lmax, fabsf(yv));
      }
    }
  }
  for (int off = 32; off; off >>= 1) lmax = fmaxf(lmax, __shfl_xor(lmax, off));
  float* fred = (float*)smem;  // K-loop fully barriered -> safe reuse
  if (lane == 0) fred[wid] = lmax;
  __syncthreads();
  if (tid == 0) {
    float m = fred[0];
#pragma unroll
    for (int i = 1; i < 8; ++i) m = fmaxf(m, fred[i]);
    atomicMax(maxY, __float_as_uint(m));
  }
#undef STAGE
#undef ASLOT
#undef BSLOT
#undef LDA
#undef LDB
#undef MFMA16
}

// ---------------- output quant in-place on d_out --------------------------------------------
__global__ __launch_bounds__(256) void quant_out_kernel(float* __restrict__ y, int n4,
                                                        const unsigned* __restrict__ slot) {
  float s = fmaxf(__uint_as_float(*slot) / 127.0f, 1e-8f);
  float inv = 1.0f / s;
  int tid = blockIdx.x * blockDim.x + threadIdx.x;
  int stride = gridDim.x * blockDim.x;
  float4* y4 = (float4*)y;
  for (int i = tid; i < n4; i += stride) {
    float4 v = y4[i];
    v.x = fminf(fmaxf(rintf(v.x * inv), -128.0f), 127.0f) * s;
    v.y = fminf(fmaxf(rintf(v.y * inv), -128.0f), 127.0f) * s;
    v.z = fminf(fmaxf(rintf(v.z * inv), -128.0f), 127.0f) * s;
    v.w = fminf(fmaxf(rintf(v.w * inv), -128.0f), 127.0f) * s;
    y4[i] = v;
  }
}

extern "C" void kernel_launch(void* const* d_in, const int* in_sizes, int n_in,
                              void* d_out, int out_size, void* d_ws, size_t ws_size,
                              hipStream_t stream) {
  const float* inp = (const float*)d_in[0];  // [8192,4096]
  const float* W = (const float*)d_in[1];    // [4096,4096]
  const float* b = (const float*)d_in[2];    // [4096]
  float* out = (float*)d_out;                // [8192,4096]

  unsigned* slots = (unsigned*)d_ws;  // [0]=max|X|, [1]=max|W|, [2]=max|Y| (float bits)
  signed char* Xq = (signed char*)d_ws + 256;
  signed char* Wq = Xq + (size_t)GM * GK;

  const int nX = GM * GK;
  const int nW = GN * GK;

  // zero the atomic-max slots (ws is NOT re-poisoned between timed replays)
  hipMemsetAsync(d_ws, 0, 16, stream);

  maxabs_kernel<<<1024, 256, 0, stream>>>(inp, nX / 4, slots + 0);
  maxabs_kernel<<<512, 256, 0, stream>>>(W, nW / 4, slots + 1);

  quant_kernel<<<1024, 256, 0, stream>>>(inp, Xq, nX / 4, slots + 0, 127.0f, -128.0f, 127.0f);
  quant_kernel<<<512, 256, 0, stream>>>(W, Wq, nW / 4, slots + 1, 7.0f, -8.0f, 7.0f);

  gemm_i8_kernel<<<NWG, 512, 0, stream>>>(Xq, Wq, b, slots, out, slots + 2);

  quant_out_kernel<<<1024, 256, 0, stream>>>(out, (GM * GN) / 4, slots + 2);
}